// Round 22
// baseline (21.073 us; speedup 1.0000x reference)
//
#include <hip/hip_runtime.h>

#define NQ 4
#define NL 4

typedef _Float16 f16x8 __attribute__((ext_vector_type(8)));
typedef float f32x16 __attribute__((ext_vector_type(16)));
typedef float f32x4  __attribute__((ext_vector_type(4)));
typedef float f32x2  __attribute__((ext_vector_type(2)));

#define INV2PI 0.15915494309189535f
#define CHUNKS 4
#define CSAMP  256          // samples per chunk (= block size)

// ---------------------------------------------------------------------------
// R20 base (18.68 us), single lever: DEDUP'd NONTEMPORAL x loads.
// Each wave loads its 64 distinct samples exactly once (lane L <- sample
// wv*64+L, no half-wave duplication), nontemporal (no L3 allocation -> no
// dirty-poison eviction), then redistributes via __shfl so both half-waves
// get their sample's angles. R19's NT regression was the duplicate-address
// confound (NT bypass double-fetched); this removes it.
// ---------------------------------------------------------------------------
__global__ __launch_bounds__(256) void qnn_fused(
    const float*  __restrict__ x,     // [B*4]
    const float*  __restrict__ w,     // [4][4][3]
    const float*  __restrict__ fcw,   // [10][4]
    const float*  __restrict__ fcb,   // [10]
    float*        __restrict__ out,   // [B*10]
    int nB)
{
  __shared__ float sM[512];               // M[32][16]
  __shared__ float sG[512];               // G[32][16]

  int t    = threadIdx.x;
  int lane = t & 63;
  int wv   = t >> 6;
  int col  = lane & 31;
  int hi   = lane >> 5;

  int base = blockIdx.x * (CHUNKS * CSAMP);

  // ---- dedup'd NT loads: one distinct sample per lane per chunk ----
  f32x4 xl[CHUNKS];
#pragma unroll
  for (int c = 0; c < CHUNKS; ++c) {
    int s = base + c * CSAMP + wv * 64 + lane;
    s = (s < nB) ? s : (nB - 1);
    xl[c] = __builtin_nontemporal_load((const f32x4*)(x + (size_t)s * 4));
  }

  // ================= parallel prelude (native trig) =================
  {
    int k = t >> 4;        // basis column 0..15
    int j = t & 15;        // state row 0..15
    int gbase = lane & 48; // lane group base for shfl

    float re = (j == k) ? 1.f : 0.f;
    float im = 0.f;

    const int ranges[4] = {1, 2, 3, 1};
#pragma unroll
    for (int l = 0; l < NL; ++l) {
#pragma unroll
      for (int q = 0; q < NQ; ++q) {
        float phi = w[l*12 + q*3 + 0];
        float th  = w[l*12 + q*3 + 1];
        float om  = w[l*12 + q*3 + 2];
        float at = th * (0.5f * INV2PI);
        float st = __builtin_amdgcn_sinf(at), ct = __builtin_amdgcn_cosf(at);
        float ap = (phi + om) * (0.5f * INV2PI);
        float spo = __builtin_amdgcn_sinf(ap), cpo = __builtin_amdgcn_cosf(ap);
        float am = (phi - om) * (0.5f * INV2PI);
        float smo = __builtin_amdgcn_sinf(am), cmo = __builtin_amdgcn_cosf(am);

        float ar = cpo*ct,  ai = -spo*ct;
        float br = -cmo*st, bi = -smo*st;
        float dr = cmo*st,  di = -smo*st;
        float er = cpo*ct,  ei = spo*ct;

        int m = 8 >> q;
        float pre = __shfl_xor(re, m);
        float pim = __shfl_xor(im, m);
        bool one = (j & m) != 0;
        float scr = one ? er : ar, sci = one ? ei : ai;
        float pcr = one ? dr : br, pci = one ? di : bi;
        float nre = scr*re - sci*im + pcr*pre - pci*pim;
        float nim = scr*im + sci*re + pcr*pim + pci*pre;
        re = nre; im = nim;
      }
      int r = ranges[l];
      int src = j;
#pragma unroll
      for (int q = 3; q >= 0; --q) {
        int mc = 8 >> q;
        int mt = 8 >> ((q + r) & 3);
        src ^= (src & mc) ? mt : 0;
      }
      re = __shfl(re, gbase + src);
      im = __shfl(im, gbase + src);
    }

    int pc = __popc(k) & 3;
    float re2, im2;
    if      (pc == 0) { re2 =  re; im2 =  im; }
    else if (pc == 1) { re2 =  im; im2 = -re; }
    else if (pc == 2) { re2 = -re; im2 = -im; }
    else              { re2 = -im; im2 =  re; }
    sM[j*16 + k]        = re2;
    sM[(16 + j)*16 + k] = im2;

    if (t < 160) {
      int o  = t >> 4;
      int kk = t & 15;
      int jj = (kk & 3) + 8 * ((kk >> 2) & 1) + 4 * (kk >> 3);
      float g = fcw[o*4 + 0] * ((jj & 8) ? -1.f : 1.f)
              + fcw[o*4 + 1] * ((jj & 4) ? -1.f : 1.f)
              + fcw[o*4 + 2] * ((jj & 2) ? -1.f : 1.f)
              + fcw[o*4 + 3] * ((jj & 1) ? -1.f : 1.f);
      sG[t] = g;
    }
    for (int i = t; i < 352; i += 256) sG[160 + i] = 0.f;
  }
  __syncthreads();

  // ---- build fragments from LDS (split-f16 M, plain-f16 G) ----
  int row = col;
  int k0  = hi * 8;
  f16x8 Ahi, Alo, Ghi;
#pragma unroll
  for (int i = 0; i < 8; ++i) {
    float v = sM[row * 16 + k0 + i];
    _Float16 h = (_Float16)v;
    Ahi[i] = h;
    Alo[i] = (_Float16)(v - (float)h);
    Ghi[i] = (_Float16)sG[row * 16 + k0 + i];
  }

  // bias: acc2 rows for this lane: hi=0 -> {0,1,2,3,8,9}, hi=1 -> {4,5,6,7}
  int o0 = hi * 4;
  float b0 = fcb[o0 + 0], b1 = fcb[o0 + 1], b2 = fcb[o0 + 2], b3 = fcb[o0 + 3];
  float b4 = hi ? 0.f : fcb[8];
  float b5 = hi ? 0.f : fcb[9];

#pragma unroll
  for (int c = 0; c < CHUNKS; ++c) {
#pragma unroll
    for (int g = 0; g < 2; ++g) {
      int sl = wv * 64 + g * 32 + col;
      int s  = base + c * CSAMP + sl;
      int srcl = g * 32 + col;     // lane holding this sample's x

      float xx = __shfl(xl[c][0], srcl, 64);
      float xy = __shfl(xl[c][1], srcl, 64);
      float xz = __shfl(xl[c][2], srcl, 64);
      float xw = __shfl(xl[c][3], srcl, 64);

      float rev0 = xx * (0.5f * INV2PI);
      float cs0  = __builtin_amdgcn_sinf(hi ? rev0 : rev0 + 0.25f);
      float rev1 = xy * (0.5f * INV2PI);
      float s1 = __builtin_amdgcn_sinf(rev1), c1 = __builtin_amdgcn_cosf(rev1);
      float rev2 = xz * (0.5f * INV2PI);
      float s2 = __builtin_amdgcn_sinf(rev2), c2 = __builtin_amdgcn_cosf(rev2);
      float rev3 = xw * (0.5f * INV2PI);
      float s3 = __builtin_amdgcn_sinf(rev3), c3 = __builtin_amdgcn_cosf(rev3);

      float a0 = cs0 * c1, a1 = cs0 * s1;
      float w0 = c2 * c3, w1 = c2 * s3, w2 = s2 * c3, w3 = s2 * s3;
      f16x8 Bf;
      Bf[0] = (_Float16)(a0 * w0); Bf[1] = (_Float16)(a0 * w1);
      Bf[2] = (_Float16)(a0 * w2); Bf[3] = (_Float16)(a0 * w3);
      Bf[4] = (_Float16)(a1 * w0); Bf[5] = (_Float16)(a1 * w1);
      Bf[6] = (_Float16)(a1 * w2); Bf[7] = (_Float16)(a1 * w3);

      f32x16 acc = {0.f,0.f,0.f,0.f,0.f,0.f,0.f,0.f,
                    0.f,0.f,0.f,0.f,0.f,0.f,0.f,0.f};
      acc = __builtin_amdgcn_mfma_f32_32x32x16_f16(Ahi, Bf, acc, 0, 0, 0);
      acc = __builtin_amdgcn_mfma_f32_32x32x16_f16(Alo, Bf, acc, 0, 0, 0);

      f16x8 Bp;
      Bp[0] = (_Float16)fmaf(acc[0], acc[0], acc[8]  * acc[8]);
      Bp[1] = (_Float16)fmaf(acc[1], acc[1], acc[9]  * acc[9]);
      Bp[2] = (_Float16)fmaf(acc[2], acc[2], acc[10] * acc[10]);
      Bp[3] = (_Float16)fmaf(acc[3], acc[3], acc[11] * acc[11]);
      Bp[4] = (_Float16)fmaf(acc[4], acc[4], acc[12] * acc[12]);
      Bp[5] = (_Float16)fmaf(acc[5], acc[5], acc[13] * acc[13]);
      Bp[6] = (_Float16)fmaf(acc[6], acc[6], acc[14] * acc[14]);
      Bp[7] = (_Float16)fmaf(acc[7], acc[7], acc[15] * acc[15]);

      f32x16 acc2 = {b0, b1, b2, b3, b4, b5, 0.f, 0.f,
                     0.f, 0.f, 0.f, 0.f, 0.f, 0.f, 0.f, 0.f};
      acc2 = __builtin_amdgcn_mfma_f32_32x32x16_f16(Ghi, Bp, acc2, 0, 0, 0);

      if (s < nB) {
        float* op = out + (size_t)s * 10 + o0;   // 8B-aligned
        f32x2 v01; v01[0] = acc2[0]; v01[1] = acc2[1];
        f32x2 v23; v23[0] = acc2[2]; v23[1] = acc2[3];
        __builtin_nontemporal_store(v01, (f32x2*)(op + 0));
        __builtin_nontemporal_store(v23, (f32x2*)(op + 2));
        if (!hi) {
          f32x2 v89; v89[0] = acc2[4]; v89[1] = acc2[5];
          __builtin_nontemporal_store(v89, (f32x2*)(out + (size_t)s * 10 + 8));
        }
      }
    }
  }
}

extern "C" void kernel_launch(void* const* d_in, const int* in_sizes, int n_in,
                              void* d_out, int out_size, void* d_ws, size_t ws_size,
                              hipStream_t stream) {
  const float* x   = (const float*)d_in[0];
  const float* w   = (const float*)d_in[1];
  const float* fcw = (const float*)d_in[2];
  const float* fcb = (const float*)d_in[3];
  float* out = (float*)d_out;
  int nB = in_sizes[0] / 4;

  int nblk = (nB + CHUNKS * CSAMP - 1) / (CHUNKS * CSAMP);
  hipLaunchKernelGGL(qnn_fused, dim3(nblk), dim3(256), 0, stream,
                     x, w, fcw, fcb, out, nB);
}

// Round 23
// 18.683 us; speedup vs baseline: 1.1279x; 1.1279x over previous
//
#include <hip/hip_runtime.h>

#define NQ 4
#define NL 4

typedef _Float16 f16x8 __attribute__((ext_vector_type(8)));
typedef float f32x16 __attribute__((ext_vector_type(16)));
typedef float f32x4  __attribute__((ext_vector_type(4)));
typedef float f32x2  __attribute__((ext_vector_type(2)));

#define INV2PI 0.15915494309189535f
#define CHUNKS 4
#define CSAMP  256          // samples per chunk (= block size)

// ---------------------------------------------------------------------------
// FINAL (R20 configuration, 18.68 us — best of 22 rounds).
// Structure: single fused kernel.
//  - all 8 x-loads issued first (normal cached loads — NT loads regress,
//    R19/R21; cache serves the half-wave duplicate addresses for free)
//  - parallel prelude: all 256 threads build M=[Re V;Im V] (thread (k,j)
//    owns psi_k[j]; Rot gates via __shfl_xor pair exchange; per-layer CNOT
//    ring composed into one lane permutation) + G (FC folded through
//    PauliZ signs, permuted to MFMA C-layout) -> LDS -> fragments
//  - per 32 samples: MFMA#1 psi=M.r (split-f16 Ahi/Alo for precision),
//    probs->f16 (C-layout == next B-layout), MFMA#2 out=G.p (+bias in acc)
//  - direct nontemporal f32x2 stores (write-once output; NT stores avoid
//    dirty-L3 allocation, +2 us — R16), zero barriers in main loop
// Steady-state body = write roofline (R12 REPEAT diagnostic: 7.3 us/pass);
// remaining cold-run cost is the harness's poisoned-L3 launch environment.
// ---------------------------------------------------------------------------
__global__ __launch_bounds__(256) void qnn_fused(
    const float4* __restrict__ x,     // [B]
    const float*  __restrict__ w,     // [4][4][3]
    const float*  __restrict__ fcw,   // [10][4]
    const float*  __restrict__ fcb,   // [10]
    float*        __restrict__ out,   // [B*10]
    int nB)
{
  __shared__ float sM[512];               // M[32][16]
  __shared__ float sG[512];               // G[32][16]

  int t    = threadIdx.x;
  int lane = t & 63;
  int wv   = t >> 6;
  int col  = lane & 31;
  int hi   = lane >> 5;

  int base = blockIdx.x * (CHUNKS * CSAMP);

  // ---- issue ALL x loads first; latency hides under the prelude ----
  float4 xv[CHUNKS][2];
#pragma unroll
  for (int c = 0; c < CHUNKS; ++c) {
#pragma unroll
    for (int g = 0; g < 2; ++g) {
      int s = base + c * CSAMP + wv * 64 + g * 32 + col;
      xv[c][g] = x[(s < nB) ? s : (nB - 1)];
    }
  }

  // ================= parallel prelude (native trig) =================
  {
    int k = t >> 4;        // basis column 0..15
    int j = t & 15;        // state row 0..15
    int gbase = lane & 48; // lane group base for shfl

    float re = (j == k) ? 1.f : 0.f;
    float im = 0.f;

    const int ranges[4] = {1, 2, 3, 1};
#pragma unroll
    for (int l = 0; l < NL; ++l) {
#pragma unroll
      for (int q = 0; q < NQ; ++q) {
        float phi = w[l*12 + q*3 + 0];
        float th  = w[l*12 + q*3 + 1];
        float om  = w[l*12 + q*3 + 2];
        float at = th * (0.5f * INV2PI);
        float st = __builtin_amdgcn_sinf(at), ct = __builtin_amdgcn_cosf(at);
        float ap = (phi + om) * (0.5f * INV2PI);
        float spo = __builtin_amdgcn_sinf(ap), cpo = __builtin_amdgcn_cosf(ap);
        float am = (phi - om) * (0.5f * INV2PI);
        float smo = __builtin_amdgcn_sinf(am), cmo = __builtin_amdgcn_cosf(am);

        float ar = cpo*ct,  ai = -spo*ct;
        float br = -cmo*st, bi = -smo*st;
        float dr = cmo*st,  di = -smo*st;
        float er = cpo*ct,  ei = spo*ct;

        int m = 8 >> q;
        float pre = __shfl_xor(re, m);
        float pim = __shfl_xor(im, m);
        bool one = (j & m) != 0;
        float scr = one ? er : ar, sci = one ? ei : ai;
        float pcr = one ? dr : br, pci = one ? di : bi;
        float nre = scr*re - sci*im + pcr*pre - pci*pim;
        float nim = scr*im + sci*re + pcr*pim + pci*pre;
        re = nre; im = nim;
      }
      int r = ranges[l];
      int src = j;
#pragma unroll
      for (int q = 3; q >= 0; --q) {
        int mc = 8 >> q;
        int mt = 8 >> ((q + r) & 3);
        src ^= (src & mc) ? mt : 0;
      }
      re = __shfl(re, gbase + src);
      im = __shfl(im, gbase + src);
    }

    int pc = __popc(k) & 3;
    float re2, im2;
    if      (pc == 0) { re2 =  re; im2 =  im; }
    else if (pc == 1) { re2 =  im; im2 = -re; }
    else if (pc == 2) { re2 = -re; im2 = -im; }
    else              { re2 = -im; im2 =  re; }
    sM[j*16 + k]        = re2;
    sM[(16 + j)*16 + k] = im2;

    if (t < 160) {
      int o  = t >> 4;
      int kk = t & 15;
      int jj = (kk & 3) + 8 * ((kk >> 2) & 1) + 4 * (kk >> 3);
      float g = fcw[o*4 + 0] * ((jj & 8) ? -1.f : 1.f)
              + fcw[o*4 + 1] * ((jj & 4) ? -1.f : 1.f)
              + fcw[o*4 + 2] * ((jj & 2) ? -1.f : 1.f)
              + fcw[o*4 + 3] * ((jj & 1) ? -1.f : 1.f);
      sG[t] = g;
    }
    for (int i = t; i < 352; i += 256) sG[160 + i] = 0.f;
  }
  __syncthreads();

  // ---- build fragments from LDS (split-f16 M, plain-f16 G) ----
  int row = col;
  int k0  = hi * 8;
  f16x8 Ahi, Alo, Ghi;
#pragma unroll
  for (int i = 0; i < 8; ++i) {
    float v = sM[row * 16 + k0 + i];
    _Float16 h = (_Float16)v;
    Ahi[i] = h;
    Alo[i] = (_Float16)(v - (float)h);
    Ghi[i] = (_Float16)sG[row * 16 + k0 + i];
  }

  // bias: acc2 rows for this lane: hi=0 -> {0,1,2,3,8,9}, hi=1 -> {4,5,6,7}
  int o0 = hi * 4;
  float b0 = fcb[o0 + 0], b1 = fcb[o0 + 1], b2 = fcb[o0 + 2], b3 = fcb[o0 + 3];
  float b4 = hi ? 0.f : fcb[8];
  float b5 = hi ? 0.f : fcb[9];

#pragma unroll
  for (int c = 0; c < CHUNKS; ++c) {
#pragma unroll
    for (int g = 0; g < 2; ++g) {
      int sl = wv * 64 + g * 32 + col;
      int s  = base + c * CSAMP + sl;
      float4 x4 = xv[c][g];

      float rev0 = x4.x * (0.5f * INV2PI);
      float cs0  = __builtin_amdgcn_sinf(hi ? rev0 : rev0 + 0.25f);
      float rev1 = x4.y * (0.5f * INV2PI);
      float s1 = __builtin_amdgcn_sinf(rev1), c1 = __builtin_amdgcn_cosf(rev1);
      float rev2 = x4.z * (0.5f * INV2PI);
      float s2 = __builtin_amdgcn_sinf(rev2), c2 = __builtin_amdgcn_cosf(rev2);
      float rev3 = x4.w * (0.5f * INV2PI);
      float s3 = __builtin_amdgcn_sinf(rev3), c3 = __builtin_amdgcn_cosf(rev3);

      float a0 = cs0 * c1, a1 = cs0 * s1;
      float w0 = c2 * c3, w1 = c2 * s3, w2 = s2 * c3, w3 = s2 * s3;
      f16x8 Bf;
      Bf[0] = (_Float16)(a0 * w0); Bf[1] = (_Float16)(a0 * w1);
      Bf[2] = (_Float16)(a0 * w2); Bf[3] = (_Float16)(a0 * w3);
      Bf[4] = (_Float16)(a1 * w0); Bf[5] = (_Float16)(a1 * w1);
      Bf[6] = (_Float16)(a1 * w2); Bf[7] = (_Float16)(a1 * w3);

      f32x16 acc = {0.f,0.f,0.f,0.f,0.f,0.f,0.f,0.f,
                    0.f,0.f,0.f,0.f,0.f,0.f,0.f,0.f};
      acc = __builtin_amdgcn_mfma_f32_32x32x16_f16(Ahi, Bf, acc, 0, 0, 0);
      acc = __builtin_amdgcn_mfma_f32_32x32x16_f16(Alo, Bf, acc, 0, 0, 0);

      f16x8 Bp;
      Bp[0] = (_Float16)fmaf(acc[0], acc[0], acc[8]  * acc[8]);
      Bp[1] = (_Float16)fmaf(acc[1], acc[1], acc[9]  * acc[9]);
      Bp[2] = (_Float16)fmaf(acc[2], acc[2], acc[10] * acc[10]);
      Bp[3] = (_Float16)fmaf(acc[3], acc[3], acc[11] * acc[11]);
      Bp[4] = (_Float16)fmaf(acc[4], acc[4], acc[12] * acc[12]);
      Bp[5] = (_Float16)fmaf(acc[5], acc[5], acc[13] * acc[13]);
      Bp[6] = (_Float16)fmaf(acc[6], acc[6], acc[14] * acc[14]);
      Bp[7] = (_Float16)fmaf(acc[7], acc[7], acc[15] * acc[15]);

      f32x16 acc2 = {b0, b1, b2, b3, b4, b5, 0.f, 0.f,
                     0.f, 0.f, 0.f, 0.f, 0.f, 0.f, 0.f, 0.f};
      acc2 = __builtin_amdgcn_mfma_f32_32x32x16_f16(Ghi, Bp, acc2, 0, 0, 0);

      if (s < nB) {
        float* op = out + (size_t)s * 10 + o0;   // 8B-aligned
        f32x2 v01; v01[0] = acc2[0]; v01[1] = acc2[1];
        f32x2 v23; v23[0] = acc2[2]; v23[1] = acc2[3];
        __builtin_nontemporal_store(v01, (f32x2*)(op + 0));
        __builtin_nontemporal_store(v23, (f32x2*)(op + 2));
        if (!hi) {
          f32x2 v89; v89[0] = acc2[4]; v89[1] = acc2[5];
          __builtin_nontemporal_store(v89, (f32x2*)(out + (size_t)s * 10 + 8));
        }
      }
    }
  }
}

extern "C" void kernel_launch(void* const* d_in, const int* in_sizes, int n_in,
                              void* d_out, int out_size, void* d_ws, size_t ws_size,
                              hipStream_t stream) {
  const float* x   = (const float*)d_in[0];
  const float* w   = (const float*)d_in[1];
  const float* fcw = (const float*)d_in[2];
  const float* fcb = (const float*)d_in[3];
  float* out = (float*)d_out;
  int nB = in_sizes[0] / 4;

  int nblk = (nB + CHUNKS * CSAMP - 1) / (CHUNKS * CSAMP);
  hipLaunchKernelGGL(qnn_fused, dim3(nblk), dim3(256), 0, stream,
                     (const float4*)x, w, fcw, fcb, out, nB);
}